// Round 1
// baseline (785.708 us; speedup 1.0000x reference)
//
#include <hip/hip_runtime.h>
#include <math.h>

#define DIM 128
#define HID 512
#define BATCHN 16384
#define NSTEPS 20
#define ROWSTRIDE 131                 // DIM + 3 aug columns
#define SLICE (BATCHN * ROWSTRIDE)    // floats per trajectory step
#define BM 64                         // batch rows per block

typedef __bf16 bf16_t;
typedef __bf16 bf16x8 __attribute__((ext_vector_type(8)));
typedef float floatx4 __attribute__((ext_vector_type(4)));

__device__ __forceinline__ float fast_tanh(float x) {
    // tanh(x) = 1 - 2/(exp(2x)+1); exact at +-inf, ~1e-6 rel err — threshold is 0.52
    float e = __expf(2.0f * x);
    return 1.0f - 2.0f / (e + 1.0f);
}

// ws layout: W1T bf16 [512][128] @0 ; W2T bf16 [128][512] @131072 ;
//            biasEff f32 [20][512] @262144   (total 303104 B)
__global__ void prep_kernel(const float* __restrict__ W1, const float* __restrict__ b1,
                            const float* __restrict__ W2, const float* __restrict__ ts,
                            bf16_t* __restrict__ W1T, bf16_t* __restrict__ W2T,
                            float* __restrict__ biasEff) {
    int tid = blockIdx.x * blockDim.x + threadIdx.x;   // 0..65535
    {   // W1T[j][k] = W1[k][j], j<512, k<128 (drop t-row, folded into bias)
        int j = tid >> 7, k = tid & 127;
        W1T[j * DIM + k] = (bf16_t)W1[k * HID + j];
    }
    {   // W2T[j][k] = W2[k][j], j<128, k<512
        int j = tid >> 9, k = tid & 511;
        W2T[j * HID + k] = (bf16_t)W2[k * DIM + j];
    }
    if (tid < NSTEPS * HID) {          // biasEff[s][j] = b1[j] + ts[s]*W1[128][j]
        int s = tid >> 9, j = tid & 511;
        biasEff[tid] = b1[j] + ts[s] * W1[DIM * HID + j];
    }
}

__global__ void init_kernel(const float* __restrict__ y0, const float* __restrict__ ts,
                            float* __restrict__ out) {
    int r = blockIdx.x;    // 16384
    int c = threadIdx.x;   // 128
    out[(size_t)r * ROWSTRIDE + c] = y0[(size_t)r * DIM + c];
    if (c < 3) out[(size_t)r * ROWSTRIDE + DIM + c] = 0.0f;
    if (r == 0 && c <= NSTEPS) out[(size_t)(NSTEPS + 1) * SLICE + c] = ts[c];
}

// LDS (bytes): ybf [64][136]bf16 @0 ; w1c [64][136]bf16 @17408 ;
//              w2c [128][72]bf16 @34816 ; hc [64][72]bf16 @53248 ; total 62464
//              U f32 [64][132] @0 (reuses ybf+w1c after MFMA loop, 33792 B)
__global__ __launch_bounds__(256, 2)
void step_kernel(int s, float* __restrict__ traj, const float* __restrict__ noises,
                 const bf16_t* __restrict__ W1T, const bf16_t* __restrict__ W2T,
                 const float* __restrict__ biasEff, const float* __restrict__ b2,
                 const float* __restrict__ ts) {
    __shared__ char smem[62464];
    bf16_t* ybf = (bf16_t*)smem;
    bf16_t* w1c = (bf16_t*)(smem + 17408);
    bf16_t* w2c = (bf16_t*)(smem + 34816);
    bf16_t* hc  = (bf16_t*)(smem + 53248);
    float*  U   = (float*)smem;

    const int tid  = threadIdx.x;
    const int lane = tid & 63;
    const int w    = tid >> 6;    // wave 0..3
    const int quad = lane >> 4;
    const int l15  = lane & 15;
    const int row0 = blockIdx.x * BM;

    const float t0 = ts[s];
    const float dt = ts[s + 1] - t0;
    const float sq = sqrtf(dt);

    const float* trajS = traj + (size_t)s * SLICE;
    float*       trajN = traj + (size_t)(s + 1) * SLICE;
    const float* noise = noises + (size_t)s * BATCHN * DIM;

    // ---- stage Y tile: fp32 global (stride-131 rows) -> bf16 LDS ----
    #pragma unroll
    for (int i = 0; i < 32; ++i) {
        int q = i * 256 + tid;
        int r = q >> 7, c = q & 127;
        ybf[r * 136 + c] = (bf16_t)trajS[(size_t)(row0 + r) * ROWSTRIDE + c];
    }
    __syncthreads();

    // ---- cache Y A-fragments in registers (reused across all 8 hidden chunks) ----
    // A layout (16x16x32): A[m = lane&15][k = quad*8 + j]
    bf16x8 a1[4][4];
    #pragma unroll
    for (int m = 0; m < 4; ++m)
        #pragma unroll
        for (int k0 = 0; k0 < 4; ++k0)
            a1[m][k0] = *(const bf16x8*)(ybf + (m * 16 + l15) * 136 + k0 * 32 + quad * 8);

    floatx4 accu[4][2];
    #pragma unroll
    for (int m = 0; m < 4; ++m)
        #pragma unroll
        for (int n = 0; n < 2; ++n)
            accu[m][n] = (floatx4){0.f, 0.f, 0.f, 0.f};

    const float* beff = biasEff + s * HID;

    for (int jc = 0; jc < HID; jc += 64) {
        // stage W1 chunk as B^T: w1c[n][k] = W1T[jc+n][k]  (n<64, k<128)
        #pragma unroll
        for (int i = 0; i < 4; ++i) {
            int chunk = i * 256 + tid;          // 1024 chunks of 8 bf16
            int n = chunk >> 4, kk = (chunk & 15) << 3;
            *(bf16x8*)(w1c + n * 136 + kk) = *(const bf16x8*)(W1T + (jc + n) * DIM + kk);
        }
        // stage W2 chunk as B^T: w2c[n][kk] = W2T[n][jc+kk]  (n<128, kk<64)
        #pragma unroll
        for (int i = 0; i < 4; ++i) {
            int chunk = i * 256 + tid;
            int n = chunk >> 3, kk = (chunk & 7) << 3;
            *(bf16x8*)(w2c + n * 72 + kk) = *(const bf16x8*)(W2T + n * HID + jc + kk);
        }
        __syncthreads();

        // ---- GEMM1: acc1 = Y @ W1c ; wave w owns hidden cols [jc+w*16, jc+w*16+16) ----
        floatx4 acc1[4];
        #pragma unroll
        for (int m = 0; m < 4; ++m) acc1[m] = (floatx4){0.f, 0.f, 0.f, 0.f};
        #pragma unroll
        for (int k0 = 0; k0 < 4; ++k0) {
            bf16x8 b = *(const bf16x8*)(w1c + (w * 16 + l15) * 136 + k0 * 32 + quad * 8);
            #pragma unroll
            for (int m = 0; m < 4; ++m)
                acc1[m] = __builtin_amdgcn_mfma_f32_16x16x32_bf16(a1[m][k0], b, acc1[m], 0, 0, 0);
        }
        // bias + tanh -> hc (A-operand layout for GEMM2): C row=quad*4+i, col=l15
        float bias = beff[jc + w * 16 + l15];
        #pragma unroll
        for (int m = 0; m < 4; ++m)
            #pragma unroll
            for (int i = 0; i < 4; ++i)
                hc[(m * 16 + quad * 4 + i) * 72 + w * 16 + l15] =
                    (bf16_t)fast_tanh(acc1[m][i] + bias);
        __syncthreads();

        // ---- GEMM2: U += Hc @ W2c ; wave w owns out cols [w*32, w*32+32) ----
        #pragma unroll
        for (int k0 = 0; k0 < 2; ++k0) {
            bf16x8 a2[4];
            #pragma unroll
            for (int m = 0; m < 4; ++m)
                a2[m] = *(const bf16x8*)(hc + (m * 16 + l15) * 72 + k0 * 32 + quad * 8);
            #pragma unroll
            for (int n = 0; n < 2; ++n) {
                bf16x8 bv = *(const bf16x8*)(w2c + (w * 32 + n * 16 + l15) * 72 + k0 * 32 + quad * 8);
                #pragma unroll
                for (int m = 0; m < 4; ++m)
                    accu[m][n] = __builtin_amdgcn_mfma_f32_16x16x32_bf16(a2[m], bv, accu[m][n], 0, 0, 0);
            }
        }
        __syncthreads();
    }

    // ---- spill U accumulators to LDS (region of ybf/w1c, both dead now) ----
    #pragma unroll
    for (int m = 0; m < 4; ++m)
        #pragma unroll
        for (int n = 0; n < 2; ++n)
            #pragma unroll
            for (int i = 0; i < 4; ++i)
                U[(m * 16 + quad * 4 + i) * 132 + w * 32 + n * 16 + l15] = accu[m][n][i];
    __syncthreads();

    // ---- epilogue: 4 threads per row, 32 cols each ----
    const int r = tid >> 2;
    const int p = tid & 3;
    const int R = row0 + r;
    const int cb = p * 32;
    const float* nrow = noise + (size_t)R * DIM + cb;
    const float* yrow = trajS + (size_t)R * ROWSTRIDE + cb;
    float*       orow = trajN + (size_t)R * ROWSTRIDE + cb;

    float udw = 0.f, en = 0.f;
    #pragma unroll
    for (int jj = 0; jj < 32; jj += 4) {
        floatx4 nz = *(const floatx4*)(nrow + jj);
        #pragma unroll
        for (int q2 = 0; q2 < 4; ++q2) {
            int c = cb + jj + q2;
            float u = U[r * 132 + c] + b2[c];
            float y = yrow[jj + q2];
            float yn = y + (u - y) * dt + sq * nz[q2];   // ALPHA=1, SIGMA=1
            orow[jj + q2] = yn;
            udw += u * nz[q2];
            en  += u * u;
        }
    }
    // reduce across the 4 column-parts (lanes r*4+p, same wave)
    udw += __shfl_xor(udw, 1);
    udw += __shfl_xor(udw, 2);
    en  += __shfl_xor(en, 1);
    en  += __shfl_xor(en, 2);
    if (p == 0) {
        const float* augp = trajS + (size_t)R * ROWSTRIDE + DIM;
        float*       augn = trajN + (size_t)R * ROWSTRIDE + DIM;
        float du = udw * sq;                 // (sq/SIGMA), SIGMA=1
        augn[0] = augp[0] + du;              // int u/sigma dW
        augn[1] = augp[1] + du;              // stop_gradient copy == same in fwd
        augn[2] = augp[2] + 0.5f * en * dt;  // energy
    }
}

extern "C" void kernel_launch(void* const* d_in, const int* in_sizes, int n_in,
                              void* d_out, int out_size, void* d_ws, size_t ws_size,
                              hipStream_t stream) {
    const float* y0     = (const float*)d_in[0];
    const float* W1     = (const float*)d_in[1];
    const float* b1     = (const float*)d_in[2];
    const float* W2     = (const float*)d_in[3];
    const float* b2     = (const float*)d_in[4];
    const float* noises = (const float*)d_in[5];
    const float* ts     = (const float*)d_in[6];
    float* out = (float*)d_out;

    bf16_t* W1T    = (bf16_t*)d_ws;                       // 131072 B
    bf16_t* W2T    = (bf16_t*)((char*)d_ws + 131072);     // 131072 B
    float*  biasEff = (float*)((char*)d_ws + 262144);     // 40960 B

    prep_kernel<<<256, 256, 0, stream>>>(W1, b1, W2, ts, W1T, W2T, biasEff);
    init_kernel<<<BATCHN, DIM, 0, stream>>>(y0, ts, out);
    for (int s = 0; s < NSTEPS; ++s) {
        step_kernel<<<BATCHN / BM, 256, 0, stream>>>(s, out, noises, W1T, W2T,
                                                     biasEff, b2, ts);
    }
}

// Round 2
// 698.935 us; speedup vs baseline: 1.1241x; 1.1241x over previous
//
#include <hip/hip_runtime.h>
#include <math.h>

#define DIM 128
#define HID 512
#define BATCHN 16384
#define NSTEPS 20
#define ROWSTRIDE 131                 // DIM + 3 aug columns
#define SLICE (BATCHN * ROWSTRIDE)    // floats per trajectory step
#define BM 32                         // batch rows per block

typedef __bf16 bf16_t;
typedef __bf16 bf16x4 __attribute__((ext_vector_type(4)));
typedef __bf16 bf16x8 __attribute__((ext_vector_type(8)));
typedef float floatx4 __attribute__((ext_vector_type(4)));

__device__ __forceinline__ float fast_tanh(float x) {
    float e = __expf(2.0f * x);
    return 1.0f - 2.0f / (e + 1.0f);
}

// ws layout: W1T bf16 [512][128] @0 ; W2T bf16 [128][512] @131072 ;
//            biasEff f32 [20][512] @262144
__global__ void prep_kernel(const float* __restrict__ W1, const float* __restrict__ b1,
                            const float* __restrict__ W2, const float* __restrict__ ts,
                            bf16_t* __restrict__ W1T, bf16_t* __restrict__ W2T,
                            float* __restrict__ biasEff) {
    int tid = blockIdx.x * blockDim.x + threadIdx.x;   // 0..65535
    {   int j = tid >> 7, k = tid & 127;               // W1T[j][k] = W1[k][j]
        W1T[j * DIM + k] = (bf16_t)W1[k * HID + j]; }
    {   int j = tid >> 9, k = tid & 511;               // W2T[j][k] = W2[k][j]
        W2T[j * HID + k] = (bf16_t)W2[k * DIM + j]; }
    if (tid < NSTEPS * HID) {                          // b1[j] + ts[s]*W1[128][j]
        int s = tid >> 9, j = tid & 511;
        biasEff[tid] = b1[j] + ts[s] * W1[DIM * HID + j];
    }
}

__global__ void init_kernel(const float* __restrict__ y0, const float* __restrict__ ts,
                            float* __restrict__ out) {
    int r = blockIdx.x;
    int c = threadIdx.x;
    out[(size_t)r * ROWSTRIDE + c] = y0[(size_t)r * DIM + c];
    if (c < 3) out[(size_t)r * ROWSTRIDE + DIM + c] = 0.0f;
    if (r == 0 && c <= NSTEPS) out[(size_t)(NSTEPS + 1) * SLICE + c] = ts[c];
}

// LDS layout (76288 B total):
//   per-wave region at w*16896: hc bf16 [32][136] (8704 B), later ALIASED by
//   Upart f32 [32][132] (16896 B) — wave-private, its own hc dead at spill.
//   ybf bf16 [32][136] @67584 (8704 B).
// Two barriers total: after Y staging, before U combine.
__global__ __launch_bounds__(256, 2)
void step_kernel(int s, float* __restrict__ traj, const float* __restrict__ noises,
                 const bf16_t* __restrict__ W1T, const bf16_t* __restrict__ W2T,
                 const float* __restrict__ biasEff, const float* __restrict__ b2,
                 const float* __restrict__ ts) {
    __shared__ char smem[76288];

    const int tid  = threadIdx.x;
    const int lane = tid & 63;
    const int w    = tid >> 6;     // wave 0..3: owns hidden slice [w*128, w*128+128)
    const int quad = lane >> 4;
    const int l15  = lane & 15;
    const int row0 = blockIdx.x * BM;

    const float dt = ts[s + 1] - ts[s];
    const float sq = sqrtf(dt);

    const float* trajS = traj + (size_t)s * SLICE;
    float*       trajN = traj + (size_t)(s + 1) * SLICE;
    const float* noise = noises + (size_t)s * BATCHN * DIM;

    bf16_t* ybf = (bf16_t*)(smem + 67584);
    bf16_t* hcw = (bf16_t*)(smem + w * 16896);

    // ---- stage Y (coalesced fp32 -> bf16 LDS), one barrier ----
    {
        int r = tid >> 3, cb = (tid & 7) * 16;
        const float* src = trajS + (size_t)(row0 + r) * ROWSTRIDE + cb;
        bf16_t* dst = ybf + r * 136 + cb;
        #pragma unroll
        for (int j = 0; j < 16; j += 4) {
            floatx4 v = *(const floatx4*)(src + j);
            bf16x4 pk;
            pk[0] = (bf16_t)v[0]; pk[1] = (bf16_t)v[1];
            pk[2] = (bf16_t)v[2]; pk[3] = (bf16_t)v[3];
            *(bf16x4*)(dst + j) = pk;
        }
    }
    __syncthreads();

    // ---- A fragments for GEMM1 (Y rows, reused across all hidden n-tiles) ----
    bf16x8 a1[2][4];
    #pragma unroll
    for (int m = 0; m < 2; ++m)
        #pragma unroll
        for (int k0 = 0; k0 < 4; ++k0)
            a1[m][k0] = *(const bf16x8*)(ybf + (m * 16 + l15) * 136 + k0 * 32 + quad * 8);

    const float*  beff = biasEff + s * HID + w * 128;
    const bf16_t* W1w  = W1T + (size_t)(w * 128) * DIM;   // wave's hidden rows
    const bf16_t* W2w  = W2T + w * 128;                   // wave's K offset

    // ---- GEMM1 + tanh -> wave-private hc (no barrier) ----
    #pragma unroll
    for (int jn = 0; jn < 8; ++jn) {
        floatx4 acc1[2];
        acc1[0] = (floatx4){0.f, 0.f, 0.f, 0.f};
        acc1[1] = (floatx4){0.f, 0.f, 0.f, 0.f};
        #pragma unroll
        for (int k0 = 0; k0 < 4; ++k0) {
            bf16x8 bv = *(const bf16x8*)(W1w + (jn * 16 + l15) * DIM + k0 * 32 + quad * 8);
            acc1[0] = __builtin_amdgcn_mfma_f32_16x16x32_bf16(a1[0][k0], bv, acc1[0], 0, 0, 0);
            acc1[1] = __builtin_amdgcn_mfma_f32_16x16x32_bf16(a1[1][k0], bv, acc1[1], 0, 0, 0);
        }
        float bias = beff[jn * 16 + l15];
        #pragma unroll
        for (int m = 0; m < 2; ++m)
            #pragma unroll
            for (int i = 0; i < 4; ++i)
                hcw[(m * 16 + quad * 4 + i) * 136 + jn * 16 + l15] =
                    (bf16_t)fast_tanh(acc1[m][i] + bias);
    }

    // ---- GEMM2: U_partial = hc @ W2 (K = this wave's 128 hidden), no barrier ----
    floatx4 accu[2][8];
    #pragma unroll
    for (int m = 0; m < 2; ++m)
        #pragma unroll
        for (int n = 0; n < 8; ++n)
            accu[m][n] = (floatx4){0.f, 0.f, 0.f, 0.f};

    #pragma unroll
    for (int k0 = 0; k0 < 4; ++k0) {
        bf16x8 a2[2];
        a2[0] = *(const bf16x8*)(hcw + l15 * 136 + k0 * 32 + quad * 8);
        a2[1] = *(const bf16x8*)(hcw + (16 + l15) * 136 + k0 * 32 + quad * 8);
        #pragma unroll
        for (int n = 0; n < 8; ++n) {
            bf16x8 bv = *(const bf16x8*)(W2w + (n * 16 + l15) * HID + k0 * 32 + quad * 8);
            accu[0][n] = __builtin_amdgcn_mfma_f32_16x16x32_bf16(a2[0], bv, accu[0][n], 0, 0, 0);
            accu[1][n] = __builtin_amdgcn_mfma_f32_16x16x32_bf16(a2[1], bv, accu[1][n], 0, 0, 0);
        }
    }

    // ---- spill partial U into this wave's region (aliases its dead hc) ----
    float* Uw = (float*)(smem + w * 16896);
    #pragma unroll
    for (int m = 0; m < 2; ++m)
        #pragma unroll
        for (int n = 0; n < 8; ++n)
            #pragma unroll
            for (int i = 0; i < 4; ++i)
                Uw[(m * 16 + quad * 4 + i) * 132 + n * 16 + l15] = accu[m][n][i];
    __syncthreads();

    // ---- epilogue: combine 4 partials + SDE update; 8 threads per row ----
    const float* Upart = (const float*)smem;
    const int r = tid >> 3;
    const int p = tid & 7;
    const int R = row0 + r;
    const int cb = p * 16;
    const float* nrow = noise + (size_t)R * DIM + cb;
    const float* yrow = trajS + (size_t)R * ROWSTRIDE + cb;
    float*       orow = trajN + (size_t)R * ROWSTRIDE + cb;

    float udw = 0.f, en = 0.f;
    #pragma unroll
    for (int j = 0; j < 16; j += 4) {
        floatx4 u4 = *(const floatx4*)(b2 + cb + j);
        #pragma unroll
        for (int ww = 0; ww < 4; ++ww) {
            floatx4 pw = *(const floatx4*)(Upart + ww * 4224 + r * 132 + cb + j);
            u4 += pw;
        }
        floatx4 nz = *(const floatx4*)(nrow + j);
        floatx4 y4 = *(const floatx4*)(yrow + j);
        floatx4 o4;
        #pragma unroll
        for (int q = 0; q < 4; ++q) {
            float u = u4[q];
            o4[q] = y4[q] + (u - y4[q]) * dt + sq * nz[q];   // ALPHA=SIGMA=1
            udw += u * nz[q];
            en  += u * u;
        }
        *(floatx4*)(orow + j) = o4;
    }
    udw += __shfl_xor(udw, 1); udw += __shfl_xor(udw, 2); udw += __shfl_xor(udw, 4);
    en  += __shfl_xor(en, 1);  en  += __shfl_xor(en, 2);  en  += __shfl_xor(en, 4);
    if (p == 0) {
        const float* augp = trajS + (size_t)R * ROWSTRIDE + DIM;
        float*       augn = trajN + (size_t)R * ROWSTRIDE + DIM;
        float du = udw * sq;
        augn[0] = augp[0] + du;
        augn[1] = augp[1] + du;
        augn[2] = augp[2] + 0.5f * en * dt;
    }
}

extern "C" void kernel_launch(void* const* d_in, const int* in_sizes, int n_in,
                              void* d_out, int out_size, void* d_ws, size_t ws_size,
                              hipStream_t stream) {
    const float* y0     = (const float*)d_in[0];
    const float* W1     = (const float*)d_in[1];
    const float* b1     = (const float*)d_in[2];
    const float* W2     = (const float*)d_in[3];
    const float* b2     = (const float*)d_in[4];
    const float* noises = (const float*)d_in[5];
    const float* ts     = (const float*)d_in[6];
    float* out = (float*)d_out;

    bf16_t* W1T     = (bf16_t*)d_ws;
    bf16_t* W2T     = (bf16_t*)((char*)d_ws + 131072);
    float*  biasEff = (float*)((char*)d_ws + 262144);

    prep_kernel<<<256, 256, 0, stream>>>(W1, b1, W2, ts, W1T, W2T, biasEff);
    init_kernel<<<BATCHN, DIM, 0, stream>>>(y0, ts, out);
    for (int s = 0; s < NSTEPS; ++s) {
        step_kernel<<<BATCHN / BM, 256, 0, stream>>>(s, out, noises, W1T, W2T,
                                                     biasEff, b2, ts);
    }
}